// Round 2
// baseline (3334.279 us; speedup 1.0000x reference)
//
#include <hip/hip_runtime.h>
#include <math.h>

#define NN 100000
#define NE 1600000
#define DIN 256
#define HD 64
#define OUTD 32
#define EMBD 128
#define SLOPE 0.2f

// ---------- helpers ----------
__device__ __forceinline__ unsigned fenc(float f) {
    unsigned u = __float_as_uint(f);
    return (u & 0x80000000u) ? ~u : (u | 0x80000000u);  // monotone float->uint
}
__device__ __forceinline__ float fdec(unsigned u) {
    unsigned v = (u & 0x80000000u) ? (u & 0x7FFFFFFFu) : ~u;
    return __uint_as_float(v);
}
__device__ __forceinline__ float lrelu(float x) { return x > 0.f ? x : SLOPE * x; }

// ---------- degree ----------
__global__ void k_degree(const int* __restrict__ dst, float* __restrict__ deg) {
    int i = blockIdx.x * blockDim.x + threadIdx.x;
    if (i < NE) atomicAdd(&deg[dst[i]], 1.0f);
}
__global__ void k_invdeg(float* __restrict__ deg) {
    int i = blockIdx.x * blockDim.x + threadIdx.x;
    if (i < NN) deg[i] = 1.0f / fmaxf(deg[i], 1.0f);
}

// ---------- F1: n2v_p = n2v @ n2v_w + b  (K=128) ----------
__global__ void k_n2vproj(const float* __restrict__ n2v, const float* __restrict__ w,
                          const float* __restrict__ b, float* __restrict__ outp) {
    __shared__ float swi[EMBD * HD];  // 32KB, interleaved k-pairs
    for (int i = threadIdx.x; i < EMBD * HD; i += blockDim.x) {
        int k = i >> 6, c = i & 63;
        swi[((k >> 1) * HD + c) * 2 + (k & 1)] = w[i];
    }
    __syncthreads();
    int t = threadIdx.x & 63;
    float bias = b[t];
    int gw = blockIdx.x * (blockDim.x >> 6) + (threadIdx.x >> 6);
    int stride = gridDim.x * (blockDim.x >> 6);
    for (int n = gw; n < NN; n += stride) {
        float2 v = ((const float2*)(n2v + (size_t)n * EMBD))[t];
        float acc = bias;
#pragma unroll 16
        for (int m = 0; m < 64; m++) {
            float b0 = __shfl(v.x, m), b1 = __shfl(v.y, m);
            float2 wp = *(const float2*)&swi[(m * HD + t) * 2];
            acc += b0 * wp.x + b1 * wp.y;
        }
        outp[(size_t)n * HD + t] = acc;
    }
}

// ---------- F2a/F2b: out = x @ w[:256] + b  (K=256, 64KB LDS) ----------
__global__ __launch_bounds__(512) void k_gemm256(const float* __restrict__ x,
                                                 const float* __restrict__ w,
                                                 const float* __restrict__ b,
                                                 float* __restrict__ out) {
    __shared__ float swi[DIN * HD];  // 16384 floats = 64KB, interleaved k-pairs
    for (int i = threadIdx.x; i < DIN * HD; i += blockDim.x) {
        int k = i >> 6, c = i & 63;
        swi[((k >> 1) * HD + c) * 2 + (k & 1)] = w[i];
    }
    __syncthreads();
    int t = threadIdx.x & 63;
    float bias = b[t];
    int gw = blockIdx.x * (blockDim.x >> 6) + (threadIdx.x >> 6);
    int stride = gridDim.x * (blockDim.x >> 6);
    for (int n = gw; n < NN; n += stride) {
        float4 xv = ((const float4*)(x + (size_t)n * DIN))[t];
        float acc = bias;
#pragma unroll 16
        for (int m2 = 0; m2 < 64; m2++) {
            float b0 = __shfl(xv.x, m2), b1 = __shfl(xv.y, m2);
            float b2 = __shfl(xv.z, m2), b3 = __shfl(xv.w, m2);
            float2 wA = *(const float2*)&swi[(m2 * 2 * HD + t) * 2];
            float2 wB = *(const float2*)&swi[((m2 * 2 + 1) * HD + t) * 2];
            acc += b0 * wA.x + b1 * wA.y + b2 * wB.x + b3 * wB.y;
        }
        out[(size_t)n * HD + t] = acc;
    }
}

// ---------- F2c: h0 = raw + sigmoid(gp1 + n2v_p@gate_w[256:]) * (n2v_p@ip_w[256:]) ----------
__global__ void k_combine(const float* __restrict__ n2vp, const float* __restrict__ rawv,
                          const float* __restrict__ gp1, const float* __restrict__ gate_w,
                          const float* __restrict__ ip_w, float* __restrict__ h0) {
    __shared__ float tw[HD * HD * 2];  // 32KB
    for (int i = threadIdx.x; i < HD * HD; i += blockDim.x) {
        int k = i >> 6, c = i & 63;
        tw[i * 2 + 0] = gate_w[(DIN + k) * HD + c];
        tw[i * 2 + 1] = ip_w[(DIN + k) * HD + c];
    }
    __syncthreads();
    int t = threadIdx.x & 63;
    int gw = blockIdx.x * (blockDim.x >> 6) + (threadIdx.x >> 6);
    int stride = gridDim.x * (blockDim.x >> 6);
    for (int n = gw; n < NN; n += stride) {
        float p = n2vp[(size_t)n * HD + t];
        float g = gp1[(size_t)n * HD + t];
        float r = rawv[(size_t)n * HD + t];
        float dacc = 0.f;
#pragma unroll 16
        for (int k = 0; k < HD; k++) {
            float bb = __shfl(p, k);
            float2 wp = *(const float2*)&tw[(k * HD + t) * 2];
            g += bb * wp.x;
            dacc += bb * wp.y;
        }
        float sg = 1.f / (1.f + expf(-g));
        h0[(size_t)n * HD + t] = r + sg * dacc;
    }
}

// ---------- scatter-add 64-wide rows, one wave per edge ----------
__global__ void k_scatter64(const int* __restrict__ src, const int* __restrict__ dst,
                            const float* __restrict__ h, float* __restrict__ acc) {
    int e = (blockIdx.x * blockDim.x + threadIdx.x) >> 6;
    int j = threadIdx.x & 63;
    if (e >= NE) return;
    int s = src[e], d = dst[e];
    atomicAdd(&acc[(size_t)d * HD + j], h[(size_t)s * HD + j]);
}

// ---------- SAGE combine (weights in LDS) ----------
__global__ void k_sage(const float* __restrict__ accv, const float* __restrict__ hin,
                       const float* __restrict__ invdeg, const float* __restrict__ wl,
                       const float* __restrict__ bl, const float* __restrict__ wr,
                       float* __restrict__ hout) {
    __shared__ float tw[HD * HD * 2];  // 32KB
    for (int i = threadIdx.x; i < HD * HD; i += blockDim.x) {
        tw[i * 2 + 0] = wl[i];
        tw[i * 2 + 1] = wr[i];
    }
    __syncthreads();
    int t = threadIdx.x & 63;
    float bias = bl[t];
    int gw = blockIdx.x * (blockDim.x >> 6) + (threadIdx.x >> 6);
    int stride = gridDim.x * (blockDim.x >> 6);
    for (int n = gw; n < NN; n += stride) {
        float id = invdeg[n];
        float sa = accv[(size_t)n * HD + t] * id;
        float sh = hin[(size_t)n * HD + t];
        float o = bias;
#pragma unroll 16
        for (int k = 0; k < HD; k++) {
            float b0 = __shfl(sa, k), b1 = __shfl(sh, k);
            float2 wp = *(const float2*)&tw[(k * HD + t) * 2];
            o += b0 * wp.x + b1 * wp.y;
        }
        hout[(size_t)n * HD + t] = fmaxf(o, 0.f);
    }
}

// ---------- GAT transform + attention scalars ----------
__global__ void k_gat_xh(const float* __restrict__ h, const float* __restrict__ w,
                         const float* __restrict__ att_s, const float* __restrict__ att_d,
                         float* __restrict__ xh, float* __restrict__ a_s, float* __restrict__ a_d) {
    __shared__ float tw[HD * HD * 2];  // 32KB: {w[k][t], w[k][64+t]}
    for (int i = threadIdx.x; i < HD * HD; i += blockDim.x) {
        int k = i >> 6, c = i & 63;
        tw[i * 2 + 0] = w[k * 128 + c];
        tw[i * 2 + 1] = w[k * 128 + 64 + c];
    }
    __syncthreads();
    int t = threadIdx.x & 63;
    float as0 = att_s[t], as1 = att_s[64 + t], ad0 = att_d[t], ad1 = att_d[64 + t];
    int gw = blockIdx.x * (blockDim.x >> 6) + (threadIdx.x >> 6);
    int stride = gridDim.x * (blockDim.x >> 6);
    for (int n = gw; n < NN; n += stride) {
        float hv = h[(size_t)n * HD + t];
        float v0 = 0.f, v1 = 0.f;
#pragma unroll 16
        for (int k = 0; k < HD; k++) {
            float bb = __shfl(hv, k);
            float2 wp = *(const float2*)&tw[(k * HD + t) * 2];
            v0 += bb * wp.x;
            v1 += bb * wp.y;
        }
        xh[(size_t)n * 128 + t] = v0;
        xh[(size_t)n * 128 + 64 + t] = v1;
        float ps0 = v0 * as0, ps1 = v1 * as1, pd0 = v0 * ad0, pd1 = v1 * ad1;
#pragma unroll
        for (int off = 32; off; off >>= 1) {
            ps0 += __shfl_xor(ps0, off);
            ps1 += __shfl_xor(ps1, off);
            pd0 += __shfl_xor(pd0, off);
            pd1 += __shfl_xor(pd1, off);
        }
        if (t == 0) {
            a_s[n * 2] = ps0; a_s[n * 2 + 1] = ps1;
            a_d[n * 2] = pd0; a_d[n * 2 + 1] = pd1;
        }
    }
}

// ---------- GAT edge kernels ----------
__global__ void k_emax(const int* __restrict__ src, const int* __restrict__ dst,
                       const float* __restrict__ a_s, const float* __restrict__ a_d,
                       unsigned* __restrict__ emax) {
    int i = blockIdx.x * blockDim.x + threadIdx.x;
    if (i >= NE + NN) return;
    int s, d;
    if (i < NE) { s = src[i]; d = dst[i]; } else { s = d = i - NE; }
    float e0 = lrelu(a_s[s * 2] + a_d[d * 2]);
    float e1 = lrelu(a_s[s * 2 + 1] + a_d[d * 2 + 1]);
    atomicMax(&emax[d * 2], fenc(e0));
    atomicMax(&emax[d * 2 + 1], fenc(e1));
}
__global__ void k_esum(const int* __restrict__ src, const int* __restrict__ dst,
                       const float* __restrict__ a_s, const float* __restrict__ a_d,
                       const unsigned* __restrict__ emax, float* __restrict__ esum) {
    int i = blockIdx.x * blockDim.x + threadIdx.x;
    if (i >= NE + NN) return;
    int s, d;
    if (i < NE) { s = src[i]; d = dst[i]; } else { s = d = i - NE; }
    float e0 = lrelu(a_s[s * 2] + a_d[d * 2]);
    float e1 = lrelu(a_s[s * 2 + 1] + a_d[d * 2 + 1]);
    atomicAdd(&esum[d * 2], expf(e0 - fdec(emax[d * 2])));
    atomicAdd(&esum[d * 2 + 1], expf(e1 - fdec(emax[d * 2 + 1])));
}
__global__ void k_gat_scatter(const int* __restrict__ src, const int* __restrict__ dst,
                              const float* __restrict__ a_s, const float* __restrict__ a_d,
                              const unsigned* __restrict__ emax, const float* __restrict__ esum,
                              const float* __restrict__ xh, float* __restrict__ acc) {
    int e = (blockIdx.x * blockDim.x + threadIdx.x) >> 6;
    int j = threadIdx.x & 63;
    if (e >= NE + NN) return;
    int s, d;
    if (e < NE) { s = src[e]; d = dst[e]; } else { s = d = e - NE; }
    float e0 = lrelu(a_s[s * 2] + a_d[d * 2]);
    float e1 = lrelu(a_s[s * 2 + 1] + a_d[d * 2 + 1]);
    float al0 = expf(e0 - fdec(emax[d * 2])) / (esum[d * 2] + 1e-16f);
    float al1 = expf(e1 - fdec(emax[d * 2 + 1])) / (esum[d * 2 + 1] + 1e-16f);
    float v = 0.5f * (al0 * xh[(size_t)s * 128 + j] + al1 * xh[(size_t)s * 128 + 64 + j]);
    atomicAdd(&acc[(size_t)d * HD + j], v);
}
__global__ void k_gat_fin(const float* __restrict__ acc, const float* __restrict__ b,
                          float* __restrict__ hout) {
    int i = blockIdx.x * blockDim.x + threadIdx.x;
    if (i < NN * HD) hout[i] = fmaxf(acc[i] + b[i & 63], 0.f);
}

// ---------- final SAGE: pre-project P = h3 @ f_wl (N x 32) ----------
__global__ void k_pfin(const float* __restrict__ h, const float* __restrict__ wl,
                       float* __restrict__ P) {
    __shared__ float sw[HD * OUTD];  // 8KB
    for (int i = threadIdx.x; i < HD * OUTD; i += blockDim.x) sw[i] = wl[i];
    __syncthreads();
    int t = threadIdx.x & 63;
    int c = t & 31, half = t >> 5;
    int gw = blockIdx.x * (blockDim.x >> 6) + (threadIdx.x >> 6);
    int stride = gridDim.x * (blockDim.x >> 6);
    for (int n = gw; n < NN; n += stride) {
        float hv = h[(size_t)n * HD + t];
        float acc = 0.f;
#pragma unroll 8
        for (int i = 0; i < 32; i++) {
            float bb = __shfl(hv, half * 32 + i);
            acc += bb * sw[half * 1024 + i * 32 + c];
        }
        acc += __shfl_xor(acc, 32);
        if (half == 0) P[(size_t)n * OUTD + c] = acc;
    }
}

// scatter-add 32-wide rows, 2 edges per wave
__global__ void k_scatter32(const int* __restrict__ src, const int* __restrict__ dst,
                            const float* __restrict__ P, float* __restrict__ accP) {
    int idx = blockIdx.x * blockDim.x + threadIdx.x;
    int e = idx >> 5, j = idx & 31;
    if (e >= NE) return;
    atomicAdd(&accP[(size_t)dst[e] * OUTD + j], P[(size_t)src[e] * OUTD + j]);
}

// out = accP*invdeg + bl + h3 @ f_wr
__global__ void k_final2(const float* __restrict__ accP, const float* __restrict__ h,
                         const float* __restrict__ invdeg, const float* __restrict__ bl,
                         const float* __restrict__ wr, float* __restrict__ out) {
    __shared__ float sw[HD * OUTD];  // 8KB
    for (int i = threadIdx.x; i < HD * OUTD; i += blockDim.x) sw[i] = wr[i];
    __syncthreads();
    int t = threadIdx.x & 63;
    int c = t & 31, half = t >> 5;
    float bias = bl[c];
    int gw = blockIdx.x * (blockDim.x >> 6) + (threadIdx.x >> 6);
    int stride = gridDim.x * (blockDim.x >> 6);
    for (int n = gw; n < NN; n += stride) {
        float hv = h[(size_t)n * HD + t];
        float acc = 0.f;
#pragma unroll 8
        for (int i = 0; i < 32; i++) {
            float bb = __shfl(hv, half * 32 + i);
            acc += bb * sw[half * 1024 + i * 32 + c];
        }
        acc += __shfl_xor(acc, 32);
        if (half == 0)
            out[(size_t)n * OUTD + c] = accP[(size_t)n * OUTD + c] * invdeg[n] + bias + acc;
    }
}

// ---------- launch ----------
extern "C" void kernel_launch(void* const* d_in, const int* in_sizes, int n_in,
                              void* d_out, int out_size, void* d_ws, size_t ws_size,
                              hipStream_t stream) {
    const float* x      = (const float*)d_in[0];
    const int*   eidx   = (const int*)d_in[1];
    const float* n2v    = (const float*)d_in[2];
    const float* n2v_w  = (const float*)d_in[3];
    const float* n2v_b  = (const float*)d_in[4];
    const float* ip_w   = (const float*)d_in[5];
    const float* ip_b   = (const float*)d_in[6];
    const float* gate_w = (const float*)d_in[7];
    const float* gate_b = (const float*)d_in[8];
    const float* s0_wl  = (const float*)d_in[9];
    const float* s0_bl  = (const float*)d_in[10];
    const float* s0_wr  = (const float*)d_in[11];
    const float* s1_wl  = (const float*)d_in[12];
    const float* s1_bl  = (const float*)d_in[13];
    const float* s1_wr  = (const float*)d_in[14];
    const float* gat_w  = (const float*)d_in[15];
    const float* att_s  = (const float*)d_in[16];
    const float* att_d  = (const float*)d_in[17];
    const float* gat_b  = (const float*)d_in[18];
    const float* f_wl   = (const float*)d_in[19];
    const float* f_bl   = (const float*)d_in[20];
    const float* f_wr   = (const float*)d_in[21];

    const int* src = eidx;
    const int* dst = eidx + NE;

    // workspace layout (floats): deg N | S1 64N | S2 64N | S3 64N | S4 128N | S5 8N
    float* ws  = (float*)d_ws;
    float* deg = ws;
    float* S1  = deg + NN;                    // n2v_p -> h1 -> h3
    float* S2  = S1 + (size_t)NN * HD;        // h0 -> h2
    float* S3  = S2 + (size_t)NN * HD;        // scatter acc; later P|accP
    float* S4  = S3 + (size_t)NN * HD;        // raw|gp1 -> xh (128N)
    float* S5  = S4 + (size_t)NN * 128;       // a_s,a_d,emax,esum (8N)

    float* n2vp = S1;
    float* rawv = S4;
    float* gp1  = S4 + (size_t)NN * HD;
    float* a_s  = S5;
    float* a_d  = S5 + (size_t)NN * 2;
    unsigned* emax = (unsigned*)(S5 + (size_t)NN * 4);
    float* esum = S5 + (size_t)NN * 6;
    float* P    = S3;
    float* accP = S3 + (size_t)NN * OUTD;

    float* out = (float*)d_out;

    const int BT = 256;
    dim3 b256(BT), b512(512);
    int eblk  = (NE + BT - 1) / BT;
    int enblk = (NE + NN + BT - 1) / BT;
    int wblk  = (NE + 3) / 4;          // wave per edge
    int wnblk = (NE + NN + 3) / 4;

    // degree
    hipMemsetAsync(deg, 0, (size_t)NN * 4, stream);
    k_degree<<<eblk, b256, 0, stream>>>(dst, deg);
    k_invdeg<<<(NN + BT - 1) / BT, b256, 0, stream>>>(deg);

    // front
    k_n2vproj<<<1280, b256, 0, stream>>>(n2v, n2v_w, n2v_b, n2vp);
    k_gemm256<<<512, b512, 0, stream>>>(x, ip_w, ip_b, rawv);
    k_gemm256<<<512, b512, 0, stream>>>(x, gate_w, gate_b, gp1);
    k_combine<<<1280, b256, 0, stream>>>(n2vp, rawv, gp1, gate_w, ip_w, S2);  // h0 -> S2

    // SAGE 0: S2 -> S1
    hipMemsetAsync(S3, 0, (size_t)NN * HD * 4, stream);
    k_scatter64<<<wblk, b256, 0, stream>>>(src, dst, S2, S3);
    k_sage<<<1280, b256, 0, stream>>>(S3, S2, deg, s0_wl, s0_bl, s0_wr, S1);

    // SAGE 1: S1 -> S2
    hipMemsetAsync(S3, 0, (size_t)NN * HD * 4, stream);
    k_scatter64<<<wblk, b256, 0, stream>>>(src, dst, S1, S3);
    k_sage<<<1280, b256, 0, stream>>>(S3, S1, deg, s1_wl, s1_bl, s1_wr, S2);

    // GAT: S2 -> S1
    k_gat_xh<<<1280, b256, 0, stream>>>(S2, gat_w, att_s, att_d, S4, a_s, a_d);
    hipMemsetAsync(emax, 0, (size_t)NN * 2 * 4, stream);
    hipMemsetAsync(esum, 0, (size_t)NN * 2 * 4, stream);
    k_emax<<<enblk, b256, 0, stream>>>(src, dst, a_s, a_d, emax);
    k_esum<<<enblk, b256, 0, stream>>>(src, dst, a_s, a_d, emax, esum);
    hipMemsetAsync(S3, 0, (size_t)NN * HD * 4, stream);
    k_gat_scatter<<<wnblk, b256, 0, stream>>>(src, dst, a_s, a_d, emax, esum, S4, S3);
    k_gat_fin<<<(NN * HD + BT - 1) / BT, b256, 0, stream>>>(S3, gat_b, S1);  // h3 -> S1

    // final SAGE: S1 -> out  (scatter pre-projected 32-wide P)
    k_pfin<<<2048, b256, 0, stream>>>(S1, f_wl, P);
    hipMemsetAsync(accP, 0, (size_t)NN * OUTD * 4, stream);
    k_scatter32<<<(NE * 32 + BT - 1) / BT, b256, 0, stream>>>(src, dst, P, accP);
    k_final2<<<2048, b256, 0, stream>>>(accP, S1, deg, f_bl, f_wr, out);
}

// Round 3
// 2337.931 us; speedup vs baseline: 1.4262x; 1.4262x over previous
//
#include <hip/hip_runtime.h>
#include <math.h>

#define NN 100000
#define NE 1600000
#define DIN 256
#define HD 64
#define OUTD 32
#define EMBD 128
#define SLOPE 0.2f

__device__ __forceinline__ float lrelu(float x) { return x > 0.f ? x : SLOPE * x; }

// ================= CSR build =================
__global__ void k_count(const int* __restrict__ dst, int* __restrict__ cnt) {
    int i = blockIdx.x * blockDim.x + threadIdx.x;
    if (i < NE) atomicAdd(&cnt[dst[i]], 1);
}

// single-block exclusive scan over NN counts -> rowptr, cursor; rowptr[NN]=NE
__global__ __launch_bounds__(1024) void k_scan(const int* __restrict__ cnt,
                                               int* __restrict__ rowptr,
                                               int* __restrict__ cursor) {
    __shared__ int part[1024];
    const int CHUNK = (NN + 1023) / 1024;  // 98
    int t = threadIdx.x;
    int begin = t * CHUNK, end = min(begin + CHUNK, NN);
    int sum = 0;
    for (int i = begin; i < end; i++) sum += cnt[i];
    part[t] = sum;
    __syncthreads();
    for (int off = 1; off < 1024; off <<= 1) {
        int v = (t >= off) ? part[t - off] : 0;
        __syncthreads();
        part[t] += v;
        __syncthreads();
    }
    int offset = (t == 0) ? 0 : part[t - 1];
    for (int i = begin; i < end; i++) {
        rowptr[i] = offset;
        cursor[i] = offset;
        offset += cnt[i];
    }
    if (t == 1023) rowptr[NN] = offset;
}

__global__ void k_fill(const int* __restrict__ src, const int* __restrict__ dst,
                       int* __restrict__ cursor, int* __restrict__ colsrc) {
    int i = blockIdx.x * blockDim.x + threadIdx.x;
    if (i >= NE) return;
    int pos = atomicAdd(&cursor[dst[i]], 1);
    colsrc[pos] = src[i];
}

__global__ void k_invdeg(const int* __restrict__ cnt, float* __restrict__ invdeg) {
    int i = blockIdx.x * blockDim.x + threadIdx.x;
    if (i < NN) invdeg[i] = 1.0f / fmaxf((float)cnt[i], 1.0f);
}

// ================= front =================
__global__ void k_n2vproj(const float* __restrict__ n2v, const float* __restrict__ w,
                          const float* __restrict__ b, float* __restrict__ outp) {
    __shared__ float swi[EMBD * HD];  // 32KB interleaved k-pairs
    for (int i = threadIdx.x; i < EMBD * HD; i += blockDim.x) {
        int k = i >> 6, c = i & 63;
        swi[((k >> 1) * HD + c) * 2 + (k & 1)] = w[i];
    }
    __syncthreads();
    int t = threadIdx.x & 63;
    float bias = b[t];
    int gw = blockIdx.x * (blockDim.x >> 6) + (threadIdx.x >> 6);
    int stride = gridDim.x * (blockDim.x >> 6);
    for (int n = gw; n < NN; n += stride) {
        float2 v = ((const float2*)(n2v + (size_t)n * EMBD))[t];
        float acc = bias;
#pragma unroll 16
        for (int m = 0; m < 64; m++) {
            float b0 = __shfl(v.x, m), b1 = __shfl(v.y, m);
            float2 wp = *(const float2*)&swi[(m * HD + t) * 2];
            acc += b0 * wp.x + b1 * wp.y;
        }
        outp[(size_t)n * HD + t] = acc;
    }
}

__global__ __launch_bounds__(512) void k_gemm256(const float* __restrict__ x,
                                                 const float* __restrict__ w,
                                                 const float* __restrict__ b,
                                                 float* __restrict__ out) {
    __shared__ float swi[DIN * HD];  // 64KB interleaved k-pairs
    for (int i = threadIdx.x; i < DIN * HD; i += blockDim.x) {
        int k = i >> 6, c = i & 63;
        swi[((k >> 1) * HD + c) * 2 + (k & 1)] = w[i];
    }
    __syncthreads();
    int t = threadIdx.x & 63;
    float bias = b[t];
    int gw = blockIdx.x * (blockDim.x >> 6) + (threadIdx.x >> 6);
    int stride = gridDim.x * (blockDim.x >> 6);
    for (int n = gw; n < NN; n += stride) {
        float4 xv = ((const float4*)(x + (size_t)n * DIN))[t];
        float acc = bias;
#pragma unroll 16
        for (int m2 = 0; m2 < 64; m2++) {
            float b0 = __shfl(xv.x, m2), b1 = __shfl(xv.y, m2);
            float b2 = __shfl(xv.z, m2), b3 = __shfl(xv.w, m2);
            float2 wA = *(const float2*)&swi[(m2 * 2 * HD + t) * 2];
            float2 wB = *(const float2*)&swi[((m2 * 2 + 1) * HD + t) * 2];
            acc += b0 * wA.x + b1 * wA.y + b2 * wB.x + b3 * wB.y;
        }
        out[(size_t)n * HD + t] = acc;
    }
}

__global__ void k_combine(const float* __restrict__ n2vp, const float* __restrict__ rawv,
                          const float* __restrict__ gp1, const float* __restrict__ gate_w,
                          const float* __restrict__ ip_w, float* __restrict__ h0) {
    __shared__ float tw[HD * HD * 2];  // 32KB
    for (int i = threadIdx.x; i < HD * HD; i += blockDim.x) {
        int k = i >> 6, c = i & 63;
        tw[i * 2 + 0] = gate_w[(DIN + k) * HD + c];
        tw[i * 2 + 1] = ip_w[(DIN + k) * HD + c];
    }
    __syncthreads();
    int t = threadIdx.x & 63;
    int gw = blockIdx.x * (blockDim.x >> 6) + (threadIdx.x >> 6);
    int stride = gridDim.x * (blockDim.x >> 6);
    for (int n = gw; n < NN; n += stride) {
        float p = n2vp[(size_t)n * HD + t];
        float g = gp1[(size_t)n * HD + t];
        float r = rawv[(size_t)n * HD + t];
        float dacc = 0.f;
#pragma unroll 16
        for (int k = 0; k < HD; k++) {
            float bb = __shfl(p, k);
            float2 wp = *(const float2*)&tw[(k * HD + t) * 2];
            g += bb * wp.x;
            dacc += bb * wp.y;
        }
        float sg = 1.f / (1.f + expf(-g));
        h0[(size_t)n * HD + t] = r + sg * dacc;
    }
}

// ================= fused SAGE: gather + mean + combine GEMM =================
__global__ void k_sage_fused(const int* __restrict__ rowptr, const int* __restrict__ colsrc,
                             const float* __restrict__ invdeg, const float* __restrict__ hin,
                             const float* __restrict__ wl, const float* __restrict__ bl,
                             const float* __restrict__ wr, float* __restrict__ hout) {
    __shared__ float tw[HD * HD * 2];  // 32KB {wl,wr}
    for (int i = threadIdx.x; i < HD * HD; i += blockDim.x) {
        tw[i * 2 + 0] = wl[i];
        tw[i * 2 + 1] = wr[i];
    }
    __syncthreads();
    int t = threadIdx.x & 63;
    float bias = bl[t];
    int gw = blockIdx.x * (blockDim.x >> 6) + (threadIdx.x >> 6);
    int stride = gridDim.x * (blockDim.x >> 6);
    for (int n = gw; n < NN; n += stride) {
        int bg = rowptr[n], en = rowptr[n + 1];
        float acc = 0.f;
        int i = bg;
        for (; i + 4 <= en; i += 4) {
            int s0 = colsrc[i], s1 = colsrc[i + 1], s2 = colsrc[i + 2], s3 = colsrc[i + 3];
            acc += hin[(size_t)s0 * HD + t] + hin[(size_t)s1 * HD + t] +
                   hin[(size_t)s2 * HD + t] + hin[(size_t)s3 * HD + t];
        }
        for (; i < en; i++) acc += hin[(size_t)colsrc[i] * HD + t];
        acc *= invdeg[n];
        float hv = hin[(size_t)n * HD + t];
        float o = bias;
#pragma unroll 16
        for (int k = 0; k < HD; k++) {
            float b0 = __shfl(acc, k), b1 = __shfl(hv, k);
            float2 wp = *(const float2*)&tw[(k * HD + t) * 2];
            o += b0 * wp.x + b1 * wp.y;
        }
        hout[(size_t)n * HD + t] = fmaxf(o, 0.f);
    }
}

// ================= GAT =================
__global__ void k_gat_xh(const float* __restrict__ h, const float* __restrict__ w,
                         const float* __restrict__ att_s, const float* __restrict__ att_d,
                         float* __restrict__ xh, float* __restrict__ a_s, float* __restrict__ a_d) {
    __shared__ float tw[HD * HD * 2];  // {w[k][t], w[k][64+t]}
    for (int i = threadIdx.x; i < HD * HD; i += blockDim.x) {
        int k = i >> 6, c = i & 63;
        tw[i * 2 + 0] = w[k * 128 + c];
        tw[i * 2 + 1] = w[k * 128 + 64 + c];
    }
    __syncthreads();
    int t = threadIdx.x & 63;
    float as0 = att_s[t], as1 = att_s[64 + t], ad0 = att_d[t], ad1 = att_d[64 + t];
    int gw = blockIdx.x * (blockDim.x >> 6) + (threadIdx.x >> 6);
    int stride = gridDim.x * (blockDim.x >> 6);
    for (int n = gw; n < NN; n += stride) {
        float hv = h[(size_t)n * HD + t];
        float v0 = 0.f, v1 = 0.f;
#pragma unroll 16
        for (int k = 0; k < HD; k++) {
            float bb = __shfl(hv, k);
            float2 wp = *(const float2*)&tw[(k * HD + t) * 2];
            v0 += bb * wp.x;
            v1 += bb * wp.y;
        }
        xh[(size_t)n * 128 + t] = v0;
        xh[(size_t)n * 128 + 64 + t] = v1;
        float ps0 = v0 * as0, ps1 = v1 * as1, pd0 = v0 * ad0, pd1 = v1 * ad1;
#pragma unroll
        for (int off = 32; off; off >>= 1) {
            ps0 += __shfl_xor(ps0, off);
            ps1 += __shfl_xor(ps1, off);
            pd0 += __shfl_xor(pd0, off);
            pd1 += __shfl_xor(pd1, off);
        }
        if (t == 0) {
            a_s[n * 2] = ps0; a_s[n * 2 + 1] = ps1;
            a_d[n * 2] = pd0; a_d[n * 2 + 1] = pd1;
        }
    }
}

// one wave per node: softmax (max, sum) lane-parallel, then serial weighted gather
__global__ void k_gat_fused(const int* __restrict__ rowptr, const int* __restrict__ colsrc,
                            const float* __restrict__ a_s, const float* __restrict__ a_d,
                            const float* __restrict__ xh, const float* __restrict__ gb,
                            float* __restrict__ hout) {
    int t = threadIdx.x & 63;
    float bias = gb[t];
    int gw = blockIdx.x * (blockDim.x >> 6) + (threadIdx.x >> 6);
    int stride = gridDim.x * (blockDim.x >> 6);
    for (int n = gw; n < NN; n += stride) {
        int bg = rowptr[n], en = rowptr[n + 1];
        float ad0 = a_d[n * 2], ad1 = a_d[n * 2 + 1];
        float self0 = lrelu(a_s[n * 2] + ad0);
        float self1 = lrelu(a_s[n * 2 + 1] + ad1);
        // phase A: max (self-loop included)
        float m0 = self0, m1 = self1;
        for (int i = bg + t; i < en; i += 64) {
            int s = colsrc[i];
            m0 = fmaxf(m0, lrelu(a_s[s * 2] + ad0));
            m1 = fmaxf(m1, lrelu(a_s[s * 2 + 1] + ad1));
        }
#pragma unroll
        for (int off = 32; off; off >>= 1) {
            m0 = fmaxf(m0, __shfl_xor(m0, off));
            m1 = fmaxf(m1, __shfl_xor(m1, off));
        }
        // phase B: exp-sum
        float s0 = 0.f, s1 = 0.f;
        for (int i = bg + t; i < en; i += 64) {
            int s = colsrc[i];
            s0 += __expf(lrelu(a_s[s * 2] + ad0) - m0);
            s1 += __expf(lrelu(a_s[s * 2 + 1] + ad1) - m1);
        }
#pragma unroll
        for (int off = 32; off; off >>= 1) {
            s0 += __shfl_xor(s0, off);
            s1 += __shfl_xor(s1, off);
        }
        s0 += __expf(self0 - m0);
        s1 += __expf(self1 - m1);
        float r0 = 0.5f / (s0 + 1e-16f), r1 = 0.5f / (s1 + 1e-16f);
        // phase C: weighted gather (self first)
        float acc = __expf(self0 - m0) * r0 * xh[(size_t)n * 128 + t] +
                    __expf(self1 - m1) * r1 * xh[(size_t)n * 128 + 64 + t];
        int i = bg;
        for (; i + 2 <= en; i += 2) {
            int sa = colsrc[i], sb = colsrc[i + 1];
            float ea0 = lrelu(a_s[sa * 2] + ad0), ea1 = lrelu(a_s[sa * 2 + 1] + ad1);
            float eb0 = lrelu(a_s[sb * 2] + ad0), eb1 = lrelu(a_s[sb * 2 + 1] + ad1);
            float xa0 = xh[(size_t)sa * 128 + t], xa1 = xh[(size_t)sa * 128 + 64 + t];
            float xb0 = xh[(size_t)sb * 128 + t], xb1 = xh[(size_t)sb * 128 + 64 + t];
            acc += __expf(ea0 - m0) * r0 * xa0 + __expf(ea1 - m1) * r1 * xa1;
            acc += __expf(eb0 - m0) * r0 * xb0 + __expf(eb1 - m1) * r1 * xb1;
        }
        for (; i < en; i++) {
            int s = colsrc[i];
            float e0 = lrelu(a_s[s * 2] + ad0), e1 = lrelu(a_s[s * 2 + 1] + ad1);
            acc += __expf(e0 - m0) * r0 * xh[(size_t)s * 128 + t] +
                   __expf(e1 - m1) * r1 * xh[(size_t)s * 128 + 64 + t];
        }
        hout[(size_t)n * HD + t] = fmaxf(acc + bias, 0.f);
    }
}

// ================= final SAGE =================
__global__ void k_pfin(const float* __restrict__ h, const float* __restrict__ wl,
                       float* __restrict__ P) {
    __shared__ float sw[HD * OUTD];
    for (int i = threadIdx.x; i < HD * OUTD; i += blockDim.x) sw[i] = wl[i];
    __syncthreads();
    int t = threadIdx.x & 63;
    int c = t & 31, half = t >> 5;
    int gw = blockIdx.x * (blockDim.x >> 6) + (threadIdx.x >> 6);
    int stride = gridDim.x * (blockDim.x >> 6);
    for (int n = gw; n < NN; n += stride) {
        float hv = h[(size_t)n * HD + t];
        float acc = 0.f;
#pragma unroll 8
        for (int i = 0; i < 32; i++) {
            float bb = __shfl(hv, half * 32 + i);
            acc += bb * sw[half * 1024 + i * 32 + c];
        }
        acc += __shfl_xor(acc, 32);
        if (half == 0) P[(size_t)n * OUTD + c] = acc;
    }
}

__global__ void k_final_fused(const int* __restrict__ rowptr, const int* __restrict__ colsrc,
                              const float* __restrict__ invdeg, const float* __restrict__ P,
                              const float* __restrict__ h, const float* __restrict__ bl,
                              const float* __restrict__ wr, float* __restrict__ out) {
    __shared__ float sw[HD * OUTD];
    for (int i = threadIdx.x; i < HD * OUTD; i += blockDim.x) sw[i] = wr[i];
    __syncthreads();
    int t = threadIdx.x & 63;
    int j = t & 31, half = t >> 5;
    float bias = bl[j];
    int gw = blockIdx.x * (blockDim.x >> 6) + (threadIdx.x >> 6);
    int stride = gridDim.x * (blockDim.x >> 6);
    for (int n = gw; n < NN; n += stride) {
        int bg = rowptr[n], en = rowptr[n + 1];
        float acc = 0.f;
        for (int i = bg + half; i < en; i += 2) acc += P[(size_t)colsrc[i] * OUTD + j];
        acc += __shfl_xor(acc, 32);  // both halves now hold the row-sum
        float hv = h[(size_t)n * HD + t];
        float o = 0.f;
#pragma unroll 8
        for (int i2 = 0; i2 < 32; i2++) {
            float bb = __shfl(hv, half * 32 + i2);
            o += bb * sw[half * 1024 + i2 * 32 + j];
        }
        o += __shfl_xor(o, 32);
        if (half == 0) out[(size_t)n * OUTD + j] = acc * invdeg[n] + bias + o;
    }
}

// ================= launch =================
extern "C" void kernel_launch(void* const* d_in, const int* in_sizes, int n_in,
                              void* d_out, int out_size, void* d_ws, size_t ws_size,
                              hipStream_t stream) {
    const float* x      = (const float*)d_in[0];
    const int*   eidx   = (const int*)d_in[1];
    const float* n2v    = (const float*)d_in[2];
    const float* n2v_w  = (const float*)d_in[3];
    const float* n2v_b  = (const float*)d_in[4];
    const float* ip_w   = (const float*)d_in[5];
    const float* ip_b   = (const float*)d_in[6];
    const float* gate_w = (const float*)d_in[7];
    const float* gate_b = (const float*)d_in[8];
    const float* s0_wl  = (const float*)d_in[9];
    const float* s0_bl  = (const float*)d_in[10];
    const float* s0_wr  = (const float*)d_in[11];
    const float* s1_wl  = (const float*)d_in[12];
    const float* s1_bl  = (const float*)d_in[13];
    const float* s1_wr  = (const float*)d_in[14];
    const float* gat_w  = (const float*)d_in[15];
    const float* att_s  = (const float*)d_in[16];
    const float* att_d  = (const float*)d_in[17];
    const float* gat_b  = (const float*)d_in[18];
    const float* f_wl   = (const float*)d_in[19];
    const float* f_bl   = (const float*)d_in[20];
    const float* f_wr   = (const float*)d_in[21];

    const int* src = eidx;
    const int* dst = eidx + NE;

    // ---- workspace layout ----
    float* ws   = (float*)d_ws;
    float* invdeg = ws;                        // NN
    float* S1   = invdeg + NN;                 // 64N
    float* S2   = S1 + (size_t)NN * HD;        // 64N
    float* S4   = S2 + (size_t)NN * HD;        // 128N (raw|gp1 -> xh)
    float* a_s  = S4 + (size_t)NN * 128;       // 2N
    float* a_d  = a_s + (size_t)NN * 2;        // 2N
    float* P    = a_d + (size_t)NN * 2;        // 32N
    int*   cnt    = (int*)(P + (size_t)NN * OUTD);  // NN
    int*   rowptr = cnt + NN;                  // NN+1
    int*   cursor = rowptr + NN + 1;           // NN
    int*   colsrc = cursor + NN;               // NE

    float* rawv = S4;
    float* gp1  = S4 + (size_t)NN * HD;
    float* out  = (float*)d_out;

    const int BT = 256;
    dim3 b256(BT), b512(512), b1024(1024);
    int eblk = (NE + BT - 1) / BT;

    // ---- CSR build ----
    hipMemsetAsync(cnt, 0, (size_t)NN * 4, stream);
    k_count<<<eblk, b256, 0, stream>>>(dst, cnt);
    k_scan<<<1, b1024, 0, stream>>>(cnt, rowptr, cursor);
    k_fill<<<eblk, b256, 0, stream>>>(src, dst, cursor, colsrc);
    k_invdeg<<<(NN + BT - 1) / BT, b256, 0, stream>>>(cnt, invdeg);

    // ---- front ----
    k_n2vproj<<<1024, b256, 0, stream>>>(n2v, n2v_w, n2v_b, S1);
    k_gemm256<<<512, b512, 0, stream>>>(x, ip_w, ip_b, rawv);
    k_gemm256<<<512, b512, 0, stream>>>(x, gate_w, gate_b, gp1);
    k_combine<<<1024, b256, 0, stream>>>(S1, rawv, gp1, gate_w, ip_w, S2);  // h0 -> S2

    // ---- SAGE 0: S2 -> S1 ----
    k_sage_fused<<<1024, b256, 0, stream>>>(rowptr, colsrc, invdeg, S2, s0_wl, s0_bl, s0_wr, S1);
    // ---- SAGE 1: S1 -> S2 ----
    k_sage_fused<<<1024, b256, 0, stream>>>(rowptr, colsrc, invdeg, S1, s1_wl, s1_bl, s1_wr, S2);

    // ---- GAT: S2 -> S1 ----
    k_gat_xh<<<1024, b256, 0, stream>>>(S2, gat_w, att_s, att_d, S4, a_s, a_d);
    k_gat_fused<<<2048, b256, 0, stream>>>(rowptr, colsrc, a_s, a_d, S4, gat_b, S1);

    // ---- final SAGE: S1 -> out ----
    k_pfin<<<2048, b256, 0, stream>>>(S1, f_wl, P);
    k_final_fused<<<2048, b256, 0, stream>>>(rowptr, colsrc, invdeg, P, S1, f_bl, f_wr, out);
}

// Round 4
// 1106.229 us; speedup vs baseline: 3.0141x; 2.1134x over previous
//
#include <hip/hip_runtime.h>
#include <math.h>

#define NN 100000
#define NE 1600000
#define DIN 256
#define HD 64
#define OUTD 32
#define EMBD 128
#define SLOPE 0.2f
#define AST 65
#define NT ((NN + 63) / 64)

__device__ __forceinline__ float lrelu(float x) { return x > 0.f ? x : SLOPE * x; }

// ================= CSR build =================
__global__ void k_count(const int* __restrict__ dst, int* __restrict__ cnt) {
    int i = blockIdx.x * blockDim.x + threadIdx.x;
    if (i < NE) atomicAdd(&cnt[dst[i]], 1);
}

__global__ __launch_bounds__(1024) void k_scan(const int* __restrict__ cnt,
                                               int* __restrict__ rowptr,
                                               int* __restrict__ cursor) {
    __shared__ int part[1024];
    const int CHUNK = (NN + 1023) / 1024;
    int t = threadIdx.x;
    int begin = t * CHUNK, end = min(begin + CHUNK, NN);
    int sum = 0;
    for (int i = begin; i < end; i++) sum += cnt[i];
    part[t] = sum;
    __syncthreads();
    for (int off = 1; off < 1024; off <<= 1) {
        int v = (t >= off) ? part[t - off] : 0;
        __syncthreads();
        part[t] += v;
        __syncthreads();
    }
    int offset = (t == 0) ? 0 : part[t - 1];
    for (int i = begin; i < end; i++) {
        rowptr[i] = offset;
        cursor[i] = offset;
        offset += cnt[i];
    }
    if (t == 1023) rowptr[NN] = offset;
}

__global__ void k_fill(const int* __restrict__ src, const int* __restrict__ dst,
                       int* __restrict__ cursor, int* __restrict__ colsrc) {
    int i = blockIdx.x * blockDim.x + threadIdx.x;
    if (i >= NE) return;
    int pos = atomicAdd(&cursor[dst[i]], 1);
    colsrc[pos] = src[i];
}

__global__ void k_invdeg(const int* __restrict__ cnt, float* __restrict__ invdeg) {
    int i = blockIdx.x * blockDim.x + threadIdx.x;
    if (i < NN) invdeg[i] = 1.0f / fmaxf((float)cnt[i], 1.0f);
}

// ================= tiled GEMM helpers =================
// stage 64x64 A chunk from row-major [N][ldg] at (nbase, koff) -> As[64][AST]
__device__ __forceinline__ void stageA(const float* __restrict__ g, int nbase, int ldg, int koff,
                                       float (*As)[AST]) {
    for (int i = threadIdx.x; i < 1024; i += 256) {
        int m = i >> 4, k4 = (i & 15) << 2;
        int row = nbase + m;
        if (row >= NN) row = NN - 1;
        float4 v = *(const float4*)&g[(size_t)row * ldg + koff + k4];
        As[m][k4] = v.x; As[m][k4 + 1] = v.y; As[m][k4 + 2] = v.z; As[m][k4 + 3] = v.w;
    }
}
// stage 64x64 contiguous W chunk (rows of row-major [K][64])
__device__ __forceinline__ void stageW(const float* __restrict__ g, float* Ws) {
    for (int i = threadIdx.x; i < 1024; i += 256) ((float4*)Ws)[i] = ((const float4*)g)[i];
}
// stage 64 rows x 64 cols from row-major [64][ldg] with col offset
__device__ __forceinline__ void stageWcols(const float* __restrict__ g, int ldg, int coff,
                                           float* Ws) {
    for (int i = threadIdx.x; i < 1024; i += 256) {
        int r = i >> 4, c4 = (i & 15) << 2;
        *(float4*)&Ws[r * 64 + c4] = *(const float4*)&g[r * ldg + coff + c4];
    }
}
// 64-step K accumulation: acc[4][4] += A[tr*4+i][k] * W[k][tc*4+j]
__device__ __forceinline__ void mac16(const float (*As)[AST], const float* __restrict__ Ws,
                                      float (*acc)[4], int tr, int tc) {
    const float* a0p = As[tr * 4 + 0];
    const float* a1p = As[tr * 4 + 1];
    const float* a2p = As[tr * 4 + 2];
    const float* a3p = As[tr * 4 + 3];
#pragma unroll 8
    for (int k = 0; k < 64; k++) {
        float4 w = *(const float4*)&Ws[k * 64 + tc * 4];
        float a0 = a0p[k], a1 = a1p[k], a2 = a2p[k], a3 = a3p[k];
        acc[0][0] += a0 * w.x; acc[0][1] += a0 * w.y; acc[0][2] += a0 * w.z; acc[0][3] += a0 * w.w;
        acc[1][0] += a1 * w.x; acc[1][1] += a1 * w.y; acc[1][2] += a1 * w.z; acc[1][3] += a1 * w.w;
        acc[2][0] += a2 * w.x; acc[2][1] += a2 * w.y; acc[2][2] += a2 * w.z; acc[2][3] += a2 * w.w;
        acc[3][0] += a3 * w.x; acc[3][1] += a3 * w.y; acc[3][2] += a3 * w.z; acc[3][3] += a3 * w.w;
    }
}

// ================= front =================
// n2vp = n2v @ n2v_w + n2v_b   (K=128)
__global__ __launch_bounds__(256) void k_n2vp_t(const float* __restrict__ n2v,
                                                const float* __restrict__ w,
                                                const float* __restrict__ b,
                                                float* __restrict__ n2vp) {
    __shared__ float As[64][AST];
    __shared__ float Ws[64 * 64];
    int nbase = blockIdx.x * 64;
    int tc = threadIdx.x & 15, tr = threadIdx.x >> 4;
    float acc[4][4] = {};
    for (int c = 0; c < 2; c++) {
        if (c) __syncthreads();
        stageA(n2v, nbase, EMBD, c * 64, As);
        stageW(w + c * 64 * 64, Ws);
        __syncthreads();
        mac16(As, Ws, acc, tr, tc);
    }
    float b0 = b[tc * 4], b1 = b[tc * 4 + 1], b2 = b[tc * 4 + 2], b3 = b[tc * 4 + 3];
#pragma unroll
    for (int i = 0; i < 4; i++) {
        int row = nbase + tr * 4 + i;
        if (row < NN) {
            float4 o = {acc[i][0] + b0, acc[i][1] + b1, acc[i][2] + b2, acc[i][3] + b3};
            *(float4*)&n2vp[(size_t)row * HD + tc * 4] = o;
        }
    }
}

// h0 = (x@ip_w[:256] + ip_b) + sigmoid(x@gate_w[:256] + n2vp@gate_w[256:] + gate_b) * (n2vp@ip_w[256:])
__global__ __launch_bounds__(256) void k_front_t(const float* __restrict__ x,
                                                 const float* __restrict__ n2vp,
                                                 const float* __restrict__ ip_w,
                                                 const float* __restrict__ ip_b,
                                                 const float* __restrict__ gate_w,
                                                 const float* __restrict__ gate_b,
                                                 float* __restrict__ h0) {
    __shared__ float As[64][AST];
    __shared__ float Ws[64 * 64];
    int nbase = blockIdx.x * 64;
    int tc = threadIdx.x & 15, tr = threadIdx.x >> 4;
    float araw[4][4] = {}, ag[4][4] = {}, adel[4][4] = {};
    for (int c = 0; c < 4; c++) {
        if (c) __syncthreads();
        stageA(x, nbase, DIN, c * 64, As);
        stageW(ip_w + c * 64 * 64, Ws);
        __syncthreads();
        mac16(As, Ws, araw, tr, tc);
        __syncthreads();
        stageW(gate_w + c * 64 * 64, Ws);
        __syncthreads();
        mac16(As, Ws, ag, tr, tc);
    }
    __syncthreads();
    stageA(n2vp, nbase, HD, 0, As);
    stageW(ip_w + DIN * 64, Ws);
    __syncthreads();
    mac16(As, Ws, adel, tr, tc);
    __syncthreads();
    stageW(gate_w + DIN * 64, Ws);
    __syncthreads();
    mac16(As, Ws, ag, tr, tc);

    float ib0 = ip_b[tc * 4], ib1 = ip_b[tc * 4 + 1], ib2 = ip_b[tc * 4 + 2], ib3 = ip_b[tc * 4 + 3];
    float gb0 = gate_b[tc * 4], gb1 = gate_b[tc * 4 + 1], gb2 = gate_b[tc * 4 + 2], gb3 = gate_b[tc * 4 + 3];
#pragma unroll
    for (int i = 0; i < 4; i++) {
        int row = nbase + tr * 4 + i;
        if (row < NN) {
            float r0 = araw[i][0] + ib0, r1 = araw[i][1] + ib1, r2 = araw[i][2] + ib2, r3 = araw[i][3] + ib3;
            float s0 = 1.f / (1.f + __expf(-(ag[i][0] + gb0)));
            float s1 = 1.f / (1.f + __expf(-(ag[i][1] + gb1)));
            float s2 = 1.f / (1.f + __expf(-(ag[i][2] + gb2)));
            float s3 = 1.f / (1.f + __expf(-(ag[i][3] + gb3)));
            float4 o = {r0 + s0 * adel[i][0], r1 + s1 * adel[i][1],
                        r2 + s2 * adel[i][2], r3 + s3 * adel[i][3]};
            *(float4*)&h0[(size_t)row * HD + tc * 4] = o;
        }
    }
}

// ================= gather mean (per node, register acc, no atomics) =================
__global__ void k_gather_mean(const int* __restrict__ rowptr, const int* __restrict__ colsrc,
                              const float* __restrict__ invdeg, const float* __restrict__ hin,
                              float* __restrict__ agg) {
    int t = threadIdx.x & 63;
    int gw = blockIdx.x * (blockDim.x >> 6) + (threadIdx.x >> 6);
    int stride = gridDim.x * (blockDim.x >> 6);
    for (int n = gw; n < NN; n += stride) {
        int bg = rowptr[n], en = rowptr[n + 1];
        float acc = 0.f;
        int i = bg;
        for (; i + 4 <= en; i += 4) {
            int s0 = colsrc[i], s1 = colsrc[i + 1], s2 = colsrc[i + 2], s3 = colsrc[i + 3];
            acc += hin[(size_t)s0 * HD + t] + hin[(size_t)s1 * HD + t] +
                   hin[(size_t)s2 * HD + t] + hin[(size_t)s3 * HD + t];
        }
        for (; i < en; i++) acc += hin[(size_t)colsrc[i] * HD + t];
        agg[(size_t)n * HD + t] = acc * invdeg[n];
    }
}

// ================= SAGE combine: relu(agg@wl + bl + h@wr) =================
__global__ __launch_bounds__(256) void k_sage_t(const float* __restrict__ agg,
                                                const float* __restrict__ h,
                                                const float* __restrict__ wl,
                                                const float* __restrict__ bl,
                                                const float* __restrict__ wr,
                                                float* __restrict__ hout) {
    __shared__ float As[64][AST];
    __shared__ float Ws[64 * 64];
    int nbase = blockIdx.x * 64;
    int tc = threadIdx.x & 15, tr = threadIdx.x >> 4;
    float acc[4][4] = {};
    stageA(agg, nbase, HD, 0, As);
    stageW(wl, Ws);
    __syncthreads();
    mac16(As, Ws, acc, tr, tc);
    __syncthreads();
    stageA(h, nbase, HD, 0, As);
    stageW(wr, Ws);
    __syncthreads();
    mac16(As, Ws, acc, tr, tc);
    float b0 = bl[tc * 4], b1 = bl[tc * 4 + 1], b2 = bl[tc * 4 + 2], b3 = bl[tc * 4 + 3];
#pragma unroll
    for (int i = 0; i < 4; i++) {
        int row = nbase + tr * 4 + i;
        if (row < NN) {
            float4 o = {fmaxf(acc[i][0] + b0, 0.f), fmaxf(acc[i][1] + b1, 0.f),
                        fmaxf(acc[i][2] + b2, 0.f), fmaxf(acc[i][3] + b3, 0.f)};
            *(float4*)&hout[(size_t)row * HD + tc * 4] = o;
        }
    }
}

// ================= GAT transform (tiled) + attention scalars =================
__global__ __launch_bounds__(256) void k_gatxh_t(const float* __restrict__ h,
                                                 const float* __restrict__ w,
                                                 const float* __restrict__ att_s,
                                                 const float* __restrict__ att_d,
                                                 float* __restrict__ xh,
                                                 float* __restrict__ a_s,
                                                 float* __restrict__ a_d) {
    __shared__ float As[64][AST];
    __shared__ float Ws[64 * 64];
    int nbase = blockIdx.x * 64;
    int tc = threadIdx.x & 15, tr = threadIdx.x >> 4;
    stageA(h, nbase, HD, 0, As);
#pragma unroll
    for (int half = 0; half < 2; half++) {
        if (half) __syncthreads();
        stageWcols(w, 128, half * 64, Ws);
        __syncthreads();
        float acc[4][4] = {};
        mac16(As, Ws, acc, tr, tc);
        float as0 = att_s[half * 64 + tc * 4], as1 = att_s[half * 64 + tc * 4 + 1];
        float as2 = att_s[half * 64 + tc * 4 + 2], as3 = att_s[half * 64 + tc * 4 + 3];
        float ad0 = att_d[half * 64 + tc * 4], ad1 = att_d[half * 64 + tc * 4 + 1];
        float ad2 = att_d[half * 64 + tc * 4 + 2], ad3 = att_d[half * 64 + tc * 4 + 3];
#pragma unroll
        for (int i = 0; i < 4; i++) {
            int row = nbase + tr * 4 + i;
            float ps = acc[i][0] * as0 + acc[i][1] * as1 + acc[i][2] * as2 + acc[i][3] * as3;
            float pd = acc[i][0] * ad0 + acc[i][1] * ad1 + acc[i][2] * ad2 + acc[i][3] * ad3;
#pragma unroll
            for (int off = 8; off; off >>= 1) {
                ps += __shfl_xor(ps, off);
                pd += __shfl_xor(pd, off);
            }
            if (row < NN) {
                *(float4*)&xh[(size_t)row * 128 + half * 64 + tc * 4] =
                    *(float4*)&acc[i][0];
                if (tc == 0) {
                    a_s[row * 2 + half] = ps;
                    a_d[row * 2 + half] = pd;
                }
            }
        }
    }
}

// ================= GAT fused softmax-gather =================
__global__ void k_gat_fused(const int* __restrict__ rowptr, const int* __restrict__ colsrc,
                            const float* __restrict__ a_s, const float* __restrict__ a_d,
                            const float* __restrict__ xh, const float* __restrict__ gb,
                            float* __restrict__ hout) {
    int t = threadIdx.x & 63;
    float bias = gb[t];
    int gw = blockIdx.x * (blockDim.x >> 6) + (threadIdx.x >> 6);
    int stride = gridDim.x * (blockDim.x >> 6);
    for (int n = gw; n < NN; n += stride) {
        int bg = rowptr[n], en = rowptr[n + 1];
        float ad0 = a_d[n * 2], ad1 = a_d[n * 2 + 1];
        float self0 = lrelu(a_s[n * 2] + ad0);
        float self1 = lrelu(a_s[n * 2 + 1] + ad1);
        float m0 = self0, m1 = self1;
        for (int i = bg + t; i < en; i += 64) {
            int s = colsrc[i];
            m0 = fmaxf(m0, lrelu(a_s[s * 2] + ad0));
            m1 = fmaxf(m1, lrelu(a_s[s * 2 + 1] + ad1));
        }
#pragma unroll
        for (int off = 32; off; off >>= 1) {
            m0 = fmaxf(m0, __shfl_xor(m0, off));
            m1 = fmaxf(m1, __shfl_xor(m1, off));
        }
        float s0 = 0.f, s1 = 0.f;
        for (int i = bg + t; i < en; i += 64) {
            int s = colsrc[i];
            s0 += __expf(lrelu(a_s[s * 2] + ad0) - m0);
            s1 += __expf(lrelu(a_s[s * 2 + 1] + ad1) - m1);
        }
#pragma unroll
        for (int off = 32; off; off >>= 1) {
            s0 += __shfl_xor(s0, off);
            s1 += __shfl_xor(s1, off);
        }
        s0 += __expf(self0 - m0);
        s1 += __expf(self1 - m1);
        float r0 = 0.5f / (s0 + 1e-16f), r1 = 0.5f / (s1 + 1e-16f);
        float acc = __expf(self0 - m0) * r0 * xh[(size_t)n * 128 + t] +
                    __expf(self1 - m1) * r1 * xh[(size_t)n * 128 + 64 + t];
        int i = bg;
        for (; i + 2 <= en; i += 2) {
            int sa = colsrc[i], sb = colsrc[i + 1];
            float ea0 = lrelu(a_s[sa * 2] + ad0), ea1 = lrelu(a_s[sa * 2 + 1] + ad1);
            float eb0 = lrelu(a_s[sb * 2] + ad0), eb1 = lrelu(a_s[sb * 2 + 1] + ad1);
            float xa0 = xh[(size_t)sa * 128 + t], xa1 = xh[(size_t)sa * 128 + 64 + t];
            float xb0 = xh[(size_t)sb * 128 + t], xb1 = xh[(size_t)sb * 128 + 64 + t];
            acc += __expf(ea0 - m0) * r0 * xa0 + __expf(ea1 - m1) * r1 * xa1;
            acc += __expf(eb0 - m0) * r0 * xb0 + __expf(eb1 - m1) * r1 * xb1;
        }
        for (; i < en; i++) {
            int s = colsrc[i];
            float e0 = lrelu(a_s[s * 2] + ad0), e1 = lrelu(a_s[s * 2 + 1] + ad1);
            acc += __expf(e0 - m0) * r0 * xh[(size_t)s * 128 + t] +
                   __expf(e1 - m1) * r1 * xh[(size_t)s * 128 + 64 + t];
        }
        hout[(size_t)n * HD + t] = fmaxf(acc + bias, 0.f);
    }
}

// ================= final SAGE =================
__global__ void k_pfin(const float* __restrict__ h, const float* __restrict__ wl,
                       float* __restrict__ P) {
    __shared__ float sw[HD * OUTD];
    for (int i = threadIdx.x; i < HD * OUTD; i += blockDim.x) sw[i] = wl[i];
    __syncthreads();
    int t = threadIdx.x & 63;
    int c = t & 31, half = t >> 5;
    int gw = blockIdx.x * (blockDim.x >> 6) + (threadIdx.x >> 6);
    int stride = gridDim.x * (blockDim.x >> 6);
    for (int n = gw; n < NN; n += stride) {
        float hv = h[(size_t)n * HD + t];
        float acc = 0.f;
#pragma unroll 8
        for (int i = 0; i < 32; i++) {
            float bb = __shfl(hv, half * 32 + i);
            acc += bb * sw[half * 1024 + i * 32 + c];
        }
        acc += __shfl_xor(acc, 32);
        if (half == 0) P[(size_t)n * OUTD + c] = acc;
    }
}

__global__ void k_final_fused(const int* __restrict__ rowptr, const int* __restrict__ colsrc,
                              const float* __restrict__ invdeg, const float* __restrict__ P,
                              const float* __restrict__ h, const float* __restrict__ bl,
                              const float* __restrict__ wr, float* __restrict__ out) {
    __shared__ float sw[HD * OUTD];
    for (int i = threadIdx.x; i < HD * OUTD; i += blockDim.x) sw[i] = wr[i];
    __syncthreads();
    int t = threadIdx.x & 63;
    int j = t & 31, half = t >> 5;
    float bias = bl[j];
    int gw = blockIdx.x * (blockDim.x >> 6) + (threadIdx.x >> 6);
    int stride = gridDim.x * (blockDim.x >> 6);
    for (int n = gw; n < NN; n += stride) {
        int bg = rowptr[n], en = rowptr[n + 1];
        float acc = 0.f;
        for (int i = bg + half; i < en; i += 2) acc += P[(size_t)colsrc[i] * OUTD + j];
        acc += __shfl_xor(acc, 32);
        float hv = h[(size_t)n * HD + t];
        float o = 0.f;
#pragma unroll 8
        for (int i2 = 0; i2 < 32; i2++) {
            float bb = __shfl(hv, half * 32 + i2);
            o += bb * sw[half * 1024 + i2 * 32 + j];
        }
        o += __shfl_xor(o, 32);
        if (half == 0) out[(size_t)n * OUTD + j] = acc * invdeg[n] + bias + o;
    }
}

// ================= launch =================
extern "C" void kernel_launch(void* const* d_in, const int* in_sizes, int n_in,
                              void* d_out, int out_size, void* d_ws, size_t ws_size,
                              hipStream_t stream) {
    const float* x      = (const float*)d_in[0];
    const int*   eidx   = (const int*)d_in[1];
    const float* n2v    = (const float*)d_in[2];
    const float* n2v_w  = (const float*)d_in[3];
    const float* n2v_b  = (const float*)d_in[4];
    const float* ip_w   = (const float*)d_in[5];
    const float* ip_b   = (const float*)d_in[6];
    const float* gate_w = (const float*)d_in[7];
    const float* gate_b = (const float*)d_in[8];
    const float* s0_wl  = (const float*)d_in[9];
    const float* s0_bl  = (const float*)d_in[10];
    const float* s0_wr  = (const float*)d_in[11];
    const float* s1_wl  = (const float*)d_in[12];
    const float* s1_bl  = (const float*)d_in[13];
    const float* s1_wr  = (const float*)d_in[14];
    const float* gat_w  = (const float*)d_in[15];
    const float* att_s  = (const float*)d_in[16];
    const float* att_d  = (const float*)d_in[17];
    const float* gat_b  = (const float*)d_in[18];
    const float* f_wl   = (const float*)d_in[19];
    const float* f_bl   = (const float*)d_in[20];
    const float* f_wr   = (const float*)d_in[21];

    const int* src = eidx;
    const int* dst = eidx + NE;

    // ---- workspace ----
    float* ws     = (float*)d_ws;
    float* invdeg = ws;                        // N
    float* S1     = invdeg + NN;               // 64N
    float* S2     = S1 + (size_t)NN * HD;      // 64N
    float* S4     = S2 + (size_t)NN * HD;      // 128N: agg | n2vp, later xh
    float* a_s    = S4 + (size_t)NN * 128;     // 2N
    float* a_d    = a_s + (size_t)NN * 2;      // 2N
    float* P      = a_d + (size_t)NN * 2;      // 32N
    int*   cnt    = (int*)(P + (size_t)NN * OUTD);
    int*   rowptr = cnt + NN;
    int*   cursor = rowptr + NN + 1;
    int*   colsrc = cursor + NN;

    float* agg  = S4;                          // 64N (SAGE phase)
    float* n2vp = S4 + (size_t)NN * HD;        // 64N (front phase)
    float* xh   = S4;                          // 128N (GAT phase)
    float* out  = (float*)d_out;

    const int BT = 256;
    dim3 b256(BT), b1024(1024);
    int eblk = (NE + BT - 1) / BT;

    // ---- CSR ----
    hipMemsetAsync(cnt, 0, (size_t)NN * 4, stream);
    k_count<<<eblk, b256, 0, stream>>>(dst, cnt);
    k_scan<<<1, b1024, 0, stream>>>(cnt, rowptr, cursor);
    k_fill<<<eblk, b256, 0, stream>>>(src, dst, cursor, colsrc);
    k_invdeg<<<(NN + BT - 1) / BT, b256, 0, stream>>>(cnt, invdeg);

    // ---- front ----
    k_n2vp_t<<<NT, b256, 0, stream>>>(n2v, n2v_w, n2v_b, n2vp);
    k_front_t<<<NT, b256, 0, stream>>>(x, n2vp, ip_w, ip_b, gate_w, gate_b, S2);  // h0 -> S2

    // ---- SAGE 0: S2 -> S1 ----
    k_gather_mean<<<2048, b256, 0, stream>>>(rowptr, colsrc, invdeg, S2, agg);
    k_sage_t<<<NT, b256, 0, stream>>>(agg, S2, s0_wl, s0_bl, s0_wr, S1);

    // ---- SAGE 1: S1 -> S2 ----
    k_gather_mean<<<2048, b256, 0, stream>>>(rowptr, colsrc, invdeg, S1, agg);
    k_sage_t<<<NT, b256, 0, stream>>>(agg, S1, s1_wl, s1_bl, s1_wr, S2);

    // ---- GAT: S2 -> S1 ----
    k_gatxh_t<<<NT, b256, 0, stream>>>(S2, gat_w, att_s, att_d, xh, a_s, a_d);
    k_gat_fused<<<2048, b256, 0, stream>>>(rowptr, colsrc, a_s, a_d, xh, gat_b, S1);

    // ---- final SAGE: S1 -> out ----
    k_pfin<<<2048, b256, 0, stream>>>(S1, f_wl, P);
    k_final_fused<<<2048, b256, 0, stream>>>(rowptr, colsrc, invdeg, P, S1, f_bl, f_wr, out);
}

// Round 5
// 879.911 us; speedup vs baseline: 3.7893x; 1.2572x over previous
//
#include <hip/hip_runtime.h>
#include <math.h>

#define NN 100000
#define NE 1600000
#define DIN 256
#define HD 64
#define OUTD 32
#define EMBD 128
#define SLOPE 0.2f
#define AST 65
#define NT ((NN + 63) / 64)
#define SCHUNK 1024
#define SNBLK ((NN + SCHUNK - 1) / SCHUNK)   // 98

__device__ __forceinline__ float lrelu(float x) { return x > 0.f ? x : SLOPE * x; }

// ================= CSR build =================
__global__ void k_count(const int* __restrict__ dst, int* __restrict__ cnt) {
    int i = blockIdx.x * blockDim.x + threadIdx.x;
    if (i < NE) atomicAdd(&cnt[dst[i]], 1);
}

// phase 1: per-block (1024-elem chunk) exclusive prefix into rowptr, block total to blksum
__global__ __launch_bounds__(256) void k_scan1(const int* __restrict__ cnt,
                                               int* __restrict__ rowptr,
                                               int* __restrict__ blksum) {
    __shared__ int ts[256];
    int base = blockIdx.x * SCHUNK + threadIdx.x * 4;
    int v0 = 0, v1 = 0, v2 = 0, v3 = 0;
    if (base < NN)     v0 = cnt[base];
    if (base + 1 < NN) v1 = cnt[base + 1];
    if (base + 2 < NN) v2 = cnt[base + 2];
    if (base + 3 < NN) v3 = cnt[base + 3];
    int s = v0 + v1 + v2 + v3;
    ts[threadIdx.x] = s;
    __syncthreads();
    for (int off = 1; off < 256; off <<= 1) {
        int w = (threadIdx.x >= off) ? ts[threadIdx.x - off] : 0;
        __syncthreads();
        ts[threadIdx.x] += w;
        __syncthreads();
    }
    int excl = ts[threadIdx.x] - s;
    if (base < NN)     rowptr[base]     = excl;
    if (base + 1 < NN) rowptr[base + 1] = excl + v0;
    if (base + 2 < NN) rowptr[base + 2] = excl + v0 + v1;
    if (base + 3 < NN) rowptr[base + 3] = excl + v0 + v1 + v2;
    if (threadIdx.x == 255) blksum[blockIdx.x] = ts[255];
}

// phase 2: single block exclusive scan of block sums (SNBLK <= 128)
__global__ __launch_bounds__(128) void k_scan2(int* __restrict__ blksum) {
    __shared__ int ts[128];
    int t = threadIdx.x;
    int v = (t < SNBLK) ? blksum[t] : 0;
    ts[t] = v;
    __syncthreads();
    for (int off = 1; off < 128; off <<= 1) {
        int w = (t >= off) ? ts[t - off] : 0;
        __syncthreads();
        ts[t] += w;
        __syncthreads();
    }
    if (t < SNBLK) blksum[t] = ts[t] - v;
}

// phase 3: add block offsets; emit cursor copy, rowptr[NN], invdeg
__global__ void k_scan3(const int* __restrict__ blksum, const int* __restrict__ cnt,
                        int* __restrict__ rowptr, int* __restrict__ cursor,
                        float* __restrict__ invdeg) {
    int i = blockIdx.x * blockDim.x + threadIdx.x;
    if (i < NN) {
        int v = rowptr[i] + blksum[i >> 10];
        rowptr[i] = v;
        cursor[i] = v;
        invdeg[i] = 1.0f / fmaxf((float)cnt[i], 1.0f);
    }
    if (i == 0) rowptr[NN] = NE;
}

__global__ void k_fill(const int* __restrict__ src, const int* __restrict__ dst,
                       int* __restrict__ cursor, int* __restrict__ colsrc) {
    int i = blockIdx.x * blockDim.x + threadIdx.x;
    if (i >= NE) return;
    int pos = atomicAdd(&cursor[dst[i]], 1);
    colsrc[pos] = src[i];
}

// ================= tiled GEMM helpers =================
__device__ __forceinline__ void stageA(const float* __restrict__ g, int nbase, int ldg, int koff,
                                       float (*As)[AST]) {
    for (int i = threadIdx.x; i < 1024; i += 256) {
        int m = i >> 4, k4 = (i & 15) << 2;
        int row = nbase + m;
        if (row >= NN) row = NN - 1;
        float4 v = *(const float4*)&g[(size_t)row * ldg + koff + k4];
        As[m][k4] = v.x; As[m][k4 + 1] = v.y; As[m][k4 + 2] = v.z; As[m][k4 + 3] = v.w;
    }
}
__device__ __forceinline__ void stageW(const float* __restrict__ g, float* Ws) {
    for (int i = threadIdx.x; i < 1024; i += 256) ((float4*)Ws)[i] = ((const float4*)g)[i];
}
__device__ __forceinline__ void stageWcols(const float* __restrict__ g, int ldg, int coff,
                                           float* Ws) {
    for (int i = threadIdx.x; i < 1024; i += 256) {
        int r = i >> 4, c4 = (i & 15) << 2;
        *(float4*)&Ws[r * 64 + c4] = *(const float4*)&g[r * ldg + coff + c4];
    }
}
__device__ __forceinline__ void mac16(const float (*As)[AST], const float* __restrict__ Ws,
                                      float (*acc)[4], int tr, int tc) {
    const float* a0p = As[tr * 4 + 0];
    const float* a1p = As[tr * 4 + 1];
    const float* a2p = As[tr * 4 + 2];
    const float* a3p = As[tr * 4 + 3];
#pragma unroll 8
    for (int k = 0; k < 64; k++) {
        float4 w = *(const float4*)&Ws[k * 64 + tc * 4];
        float a0 = a0p[k], a1 = a1p[k], a2 = a2p[k], a3 = a3p[k];
        acc[0][0] += a0 * w.x; acc[0][1] += a0 * w.y; acc[0][2] += a0 * w.z; acc[0][3] += a0 * w.w;
        acc[1][0] += a1 * w.x; acc[1][1] += a1 * w.y; acc[1][2] += a1 * w.z; acc[1][3] += a1 * w.w;
        acc[2][0] += a2 * w.x; acc[2][1] += a2 * w.y; acc[2][2] += a2 * w.z; acc[2][3] += a2 * w.w;
        acc[3][0] += a3 * w.x; acc[3][1] += a3 * w.y; acc[3][2] += a3 * w.z; acc[3][3] += a3 * w.w;
    }
}

// ================= front =================
__global__ __launch_bounds__(256) void k_n2vp_t(const float* __restrict__ n2v,
                                                const float* __restrict__ w,
                                                const float* __restrict__ b,
                                                float* __restrict__ n2vp) {
    __shared__ float As[64][AST];
    __shared__ float Ws[64 * 64];
    int nbase = blockIdx.x * 64;
    int tc = threadIdx.x & 15, tr = threadIdx.x >> 4;
    float acc[4][4] = {};
    for (int c = 0; c < 2; c++) {
        if (c) __syncthreads();
        stageA(n2v, nbase, EMBD, c * 64, As);
        stageW(w + c * 64 * 64, Ws);
        __syncthreads();
        mac16(As, Ws, acc, tr, tc);
    }
    float b0 = b[tc * 4], b1 = b[tc * 4 + 1], b2 = b[tc * 4 + 2], b3 = b[tc * 4 + 3];
#pragma unroll
    for (int i = 0; i < 4; i++) {
        int row = nbase + tr * 4 + i;
        if (row < NN) {
            float4 o = {acc[i][0] + b0, acc[i][1] + b1, acc[i][2] + b2, acc[i][3] + b3};
            *(float4*)&n2vp[(size_t)row * HD + tc * 4] = o;
        }
    }
}

__global__ __launch_bounds__(256) void k_front_t(const float* __restrict__ x,
                                                 const float* __restrict__ n2vp,
                                                 const float* __restrict__ ip_w,
                                                 const float* __restrict__ ip_b,
                                                 const float* __restrict__ gate_w,
                                                 const float* __restrict__ gate_b,
                                                 float* __restrict__ h0) {
    __shared__ float As[64][AST];
    __shared__ float Ws[64 * 64];
    int nbase = blockIdx.x * 64;
    int tc = threadIdx.x & 15, tr = threadIdx.x >> 4;
    float araw[4][4] = {}, ag[4][4] = {}, adel[4][4] = {};
    for (int c = 0; c < 4; c++) {
        if (c) __syncthreads();
        stageA(x, nbase, DIN, c * 64, As);
        stageW(ip_w + c * 64 * 64, Ws);
        __syncthreads();
        mac16(As, Ws, araw, tr, tc);
        __syncthreads();
        stageW(gate_w + c * 64 * 64, Ws);
        __syncthreads();
        mac16(As, Ws, ag, tr, tc);
    }
    __syncthreads();
    stageA(n2vp, nbase, HD, 0, As);
    stageW(ip_w + DIN * 64, Ws);
    __syncthreads();
    mac16(As, Ws, adel, tr, tc);
    __syncthreads();
    stageW(gate_w + DIN * 64, Ws);
    __syncthreads();
    mac16(As, Ws, ag, tr, tc);

    float ib0 = ip_b[tc * 4], ib1 = ip_b[tc * 4 + 1], ib2 = ip_b[tc * 4 + 2], ib3 = ip_b[tc * 4 + 3];
    float gb0 = gate_b[tc * 4], gb1 = gate_b[tc * 4 + 1], gb2 = gate_b[tc * 4 + 2], gb3 = gate_b[tc * 4 + 3];
#pragma unroll
    for (int i = 0; i < 4; i++) {
        int row = nbase + tr * 4 + i;
        if (row < NN) {
            float r0 = araw[i][0] + ib0, r1 = araw[i][1] + ib1, r2 = araw[i][2] + ib2, r3 = araw[i][3] + ib3;
            float s0 = 1.f / (1.f + __expf(-(ag[i][0] + gb0)));
            float s1 = 1.f / (1.f + __expf(-(ag[i][1] + gb1)));
            float s2 = 1.f / (1.f + __expf(-(ag[i][2] + gb2)));
            float s3 = 1.f / (1.f + __expf(-(ag[i][3] + gb3)));
            float4 o = {r0 + s0 * adel[i][0], r1 + s1 * adel[i][1],
                        r2 + s2 * adel[i][2], r3 + s3 * adel[i][3]};
            *(float4*)&h0[(size_t)row * HD + tc * 4] = o;
        }
    }
}

// ================= gather mean =================
__global__ void k_gather_mean(const int* __restrict__ rowptr, const int* __restrict__ colsrc,
                              const float* __restrict__ invdeg, const float* __restrict__ hin,
                              float* __restrict__ agg) {
    int t = threadIdx.x & 63;
    int gw = blockIdx.x * (blockDim.x >> 6) + (threadIdx.x >> 6);
    int stride = gridDim.x * (blockDim.x >> 6);
    for (int n = gw; n < NN; n += stride) {
        int bg = rowptr[n], en = rowptr[n + 1];
        float acc = 0.f;
        int i = bg;
        for (; i + 4 <= en; i += 4) {
            int s0 = colsrc[i], s1 = colsrc[i + 1], s2 = colsrc[i + 2], s3 = colsrc[i + 3];
            acc += hin[(size_t)s0 * HD + t] + hin[(size_t)s1 * HD + t] +
                   hin[(size_t)s2 * HD + t] + hin[(size_t)s3 * HD + t];
        }
        for (; i < en; i++) acc += hin[(size_t)colsrc[i] * HD + t];
        agg[(size_t)n * HD + t] = acc * invdeg[n];
    }
}

// ================= SAGE combine =================
__global__ __launch_bounds__(256) void k_sage_t(const float* __restrict__ agg,
                                                const float* __restrict__ h,
                                                const float* __restrict__ wl,
                                                const float* __restrict__ bl,
                                                const float* __restrict__ wr,
                                                float* __restrict__ hout) {
    __shared__ float As[64][AST];
    __shared__ float Ws[64 * 64];
    int nbase = blockIdx.x * 64;
    int tc = threadIdx.x & 15, tr = threadIdx.x >> 4;
    float acc[4][4] = {};
    stageA(agg, nbase, HD, 0, As);
    stageW(wl, Ws);
    __syncthreads();
    mac16(As, Ws, acc, tr, tc);
    __syncthreads();
    stageA(h, nbase, HD, 0, As);
    stageW(wr, Ws);
    __syncthreads();
    mac16(As, Ws, acc, tr, tc);
    float b0 = bl[tc * 4], b1 = bl[tc * 4 + 1], b2 = bl[tc * 4 + 2], b3 = bl[tc * 4 + 3];
#pragma unroll
    for (int i = 0; i < 4; i++) {
        int row = nbase + tr * 4 + i;
        if (row < NN) {
            float4 o = {fmaxf(acc[i][0] + b0, 0.f), fmaxf(acc[i][1] + b1, 0.f),
                        fmaxf(acc[i][2] + b2, 0.f), fmaxf(acc[i][3] + b3, 0.f)};
            *(float4*)&hout[(size_t)row * HD + tc * 4] = o;
        }
    }
}

// ================= GAT transform =================
__global__ __launch_bounds__(256) void k_gatxh_t(const float* __restrict__ h,
                                                 const float* __restrict__ w,
                                                 const float* __restrict__ att_s,
                                                 const float* __restrict__ att_d,
                                                 float* __restrict__ xh,
                                                 float* __restrict__ a_s,
                                                 float* __restrict__ a_d) {
    __shared__ float As[64][AST];
    __shared__ float Ws[64 * 64];
    int nbase = blockIdx.x * 64;
    int tc = threadIdx.x & 15, tr = threadIdx.x >> 4;
    stageA(h, nbase, HD, 0, As);
#pragma unroll
    for (int half = 0; half < 2; half++) {
        if (half) __syncthreads();
        stageWcols(w, 128, half * 64, Ws);
        __syncthreads();
        float acc[4][4] = {};
        mac16(As, Ws, acc, tr, tc);
        float as0 = att_s[half * 64 + tc * 4], as1 = att_s[half * 64 + tc * 4 + 1];
        float as2 = att_s[half * 64 + tc * 4 + 2], as3 = att_s[half * 64 + tc * 4 + 3];
        float ad0 = att_d[half * 64 + tc * 4], ad1 = att_d[half * 64 + tc * 4 + 1];
        float ad2 = att_d[half * 64 + tc * 4 + 2], ad3 = att_d[half * 64 + tc * 4 + 3];
#pragma unroll
        for (int i = 0; i < 4; i++) {
            int row = nbase + tr * 4 + i;
            float ps = acc[i][0] * as0 + acc[i][1] * as1 + acc[i][2] * as2 + acc[i][3] * as3;
            float pd = acc[i][0] * ad0 + acc[i][1] * ad1 + acc[i][2] * ad2 + acc[i][3] * ad3;
#pragma unroll
            for (int off = 8; off; off >>= 1) {
                ps += __shfl_xor(ps, off);
                pd += __shfl_xor(pd, off);
            }
            if (row < NN) {
                *(float4*)&xh[(size_t)row * 128 + half * 64 + tc * 4] = *(float4*)&acc[i][0];
                if (tc == 0) {
                    a_s[row * 2 + half] = ps;
                    a_d[row * 2 + half] = pd;
                }
            }
        }
    }
}

// ================= GAT fused softmax-gather =================
__global__ void k_gat_fused(const int* __restrict__ rowptr, const int* __restrict__ colsrc,
                            const float* __restrict__ a_s, const float* __restrict__ a_d,
                            const float* __restrict__ xh, const float* __restrict__ gb,
                            float* __restrict__ hout) {
    int t = threadIdx.x & 63;
    float bias = gb[t];
    int gw = blockIdx.x * (blockDim.x >> 6) + (threadIdx.x >> 6);
    int stride = gridDim.x * (blockDim.x >> 6);
    for (int n = gw; n < NN; n += stride) {
        int bg = rowptr[n], en = rowptr[n + 1];
        float ad0 = a_d[n * 2], ad1 = a_d[n * 2 + 1];
        float self0 = lrelu(a_s[n * 2] + ad0);
        float self1 = lrelu(a_s[n * 2 + 1] + ad1);
        float m0 = self0, m1 = self1;
        for (int i = bg + t; i < en; i += 64) {
            int s = colsrc[i];
            m0 = fmaxf(m0, lrelu(a_s[s * 2] + ad0));
            m1 = fmaxf(m1, lrelu(a_s[s * 2 + 1] + ad1));
        }
#pragma unroll
        for (int off = 32; off; off >>= 1) {
            m0 = fmaxf(m0, __shfl_xor(m0, off));
            m1 = fmaxf(m1, __shfl_xor(m1, off));
        }
        float s0 = 0.f, s1 = 0.f;
        for (int i = bg + t; i < en; i += 64) {
            int s = colsrc[i];
            s0 += __expf(lrelu(a_s[s * 2] + ad0) - m0);
            s1 += __expf(lrelu(a_s[s * 2 + 1] + ad1) - m1);
        }
#pragma unroll
        for (int off = 32; off; off >>= 1) {
            s0 += __shfl_xor(s0, off);
            s1 += __shfl_xor(s1, off);
        }
        s0 += __expf(self0 - m0);
        s1 += __expf(self1 - m1);
        float r0 = 0.5f / (s0 + 1e-16f), r1 = 0.5f / (s1 + 1e-16f);
        float acc = __expf(self0 - m0) * r0 * xh[(size_t)n * 128 + t] +
                    __expf(self1 - m1) * r1 * xh[(size_t)n * 128 + 64 + t];
        int i = bg;
        for (; i + 2 <= en; i += 2) {
            int sa = colsrc[i], sb = colsrc[i + 1];
            float ea0 = lrelu(a_s[sa * 2] + ad0), ea1 = lrelu(a_s[sa * 2 + 1] + ad1);
            float eb0 = lrelu(a_s[sb * 2] + ad0), eb1 = lrelu(a_s[sb * 2 + 1] + ad1);
            float xa0 = xh[(size_t)sa * 128 + t], xa1 = xh[(size_t)sa * 128 + 64 + t];
            float xb0 = xh[(size_t)sb * 128 + t], xb1 = xh[(size_t)sb * 128 + 64 + t];
            acc += __expf(ea0 - m0) * r0 * xa0 + __expf(ea1 - m1) * r1 * xa1;
            acc += __expf(eb0 - m0) * r0 * xb0 + __expf(eb1 - m1) * r1 * xb1;
        }
        for (; i < en; i++) {
            int s = colsrc[i];
            float e0 = lrelu(a_s[s * 2] + ad0), e1 = lrelu(a_s[s * 2 + 1] + ad1);
            acc += __expf(e0 - m0) * r0 * xh[(size_t)s * 128 + t] +
                   __expf(e1 - m1) * r1 * xh[(size_t)s * 128 + 64 + t];
        }
        hout[(size_t)n * HD + t] = fmaxf(acc + bias, 0.f);
    }
}

// ================= final SAGE =================
__global__ void k_pfin(const float* __restrict__ h, const float* __restrict__ wl,
                       float* __restrict__ P) {
    __shared__ float sw[HD * OUTD];
    for (int i = threadIdx.x; i < HD * OUTD; i += blockDim.x) sw[i] = wl[i];
    __syncthreads();
    int t = threadIdx.x & 63;
    int c = t & 31, half = t >> 5;
    int gw = blockIdx.x * (blockDim.x >> 6) + (threadIdx.x >> 6);
    int stride = gridDim.x * (blockDim.x >> 6);
    for (int n = gw; n < NN; n += stride) {
        float hv = h[(size_t)n * HD + t];
        float acc = 0.f;
#pragma unroll 8
        for (int i = 0; i < 32; i++) {
            float bb = __shfl(hv, half * 32 + i);
            acc += bb * sw[half * 1024 + i * 32 + c];
        }
        acc += __shfl_xor(acc, 32);
        if (half == 0) P[(size_t)n * OUTD + c] = acc;
    }
}

__global__ void k_final_fused(const int* __restrict__ rowptr, const int* __restrict__ colsrc,
                              const float* __restrict__ invdeg, const float* __restrict__ P,
                              const float* __restrict__ h, const float* __restrict__ bl,
                              const float* __restrict__ wr, float* __restrict__ out) {
    __shared__ float sw[HD * OUTD];
    for (int i = threadIdx.x; i < HD * OUTD; i += blockDim.x) sw[i] = wr[i];
    __syncthreads();
    int t = threadIdx.x & 63;
    int j = t & 31, half = t >> 5;
    float bias = bl[j];
    int gw = blockIdx.x * (blockDim.x >> 6) + (threadIdx.x >> 6);
    int stride = gridDim.x * (blockDim.x >> 6);
    for (int n = gw; n < NN; n += stride) {
        int bg = rowptr[n], en = rowptr[n + 1];
        float acc = 0.f;
        for (int i = bg + half; i < en; i += 2) acc += P[(size_t)colsrc[i] * OUTD + j];
        acc += __shfl_xor(acc, 32);
        float hv = h[(size_t)n * HD + t];
        float o = 0.f;
#pragma unroll 8
        for (int i2 = 0; i2 < 32; i2++) {
            float bb = __shfl(hv, half * 32 + i2);
            o += bb * sw[half * 1024 + i2 * 32 + j];
        }
        o += __shfl_xor(o, 32);
        if (half == 0) out[(size_t)n * OUTD + j] = acc * invdeg[n] + bias + o;
    }
}

// ================= launch =================
extern "C" void kernel_launch(void* const* d_in, const int* in_sizes, int n_in,
                              void* d_out, int out_size, void* d_ws, size_t ws_size,
                              hipStream_t stream) {
    const float* x      = (const float*)d_in[0];
    const int*   eidx   = (const int*)d_in[1];
    const float* n2v    = (const float*)d_in[2];
    const float* n2v_w  = (const float*)d_in[3];
    const float* n2v_b  = (const float*)d_in[4];
    const float* ip_w   = (const float*)d_in[5];
    const float* ip_b   = (const float*)d_in[6];
    const float* gate_w = (const float*)d_in[7];
    const float* gate_b = (const float*)d_in[8];
    const float* s0_wl  = (const float*)d_in[9];
    const float* s0_bl  = (const float*)d_in[10];
    const float* s0_wr  = (const float*)d_in[11];
    const float* s1_wl  = (const float*)d_in[12];
    const float* s1_bl  = (const float*)d_in[13];
    const float* s1_wr  = (const float*)d_in[14];
    const float* gat_w  = (const float*)d_in[15];
    const float* att_s  = (const float*)d_in[16];
    const float* att_d  = (const float*)d_in[17];
    const float* gat_b  = (const float*)d_in[18];
    const float* f_wl   = (const float*)d_in[19];
    const float* f_bl   = (const float*)d_in[20];
    const float* f_wr   = (const float*)d_in[21];

    const int* src = eidx;
    const int* dst = eidx + NE;

    // ---- workspace ----
    float* ws     = (float*)d_ws;
    float* invdeg = ws;                        // N
    float* S1     = invdeg + NN;               // 64N
    float* S2     = S1 + (size_t)NN * HD;      // 64N
    float* S4     = S2 + (size_t)NN * HD;      // 128N
    float* a_s    = S4 + (size_t)NN * 128;     // 2N
    float* a_d    = a_s + (size_t)NN * 2;      // 2N
    float* P      = a_d + (size_t)NN * 2;      // 32N
    int*   cnt    = (int*)(P + (size_t)NN * OUTD);
    int*   rowptr = cnt + NN;
    int*   cursor = rowptr + NN + 1;
    int*   blksum = cursor + NN;               // 128
    int*   colsrc = blksum + 128;              // NE

    float* agg  = S4;
    float* n2vp = S4 + (size_t)NN * HD;
    float* xh   = S4;
    float* out  = (float*)d_out;

    const int BT = 256;
    dim3 b128(128), b256(BT);
    int eblk = (NE + BT - 1) / BT;
    int nblk = (NN + BT - 1) / BT;

    // ---- CSR ----
    hipMemsetAsync(cnt, 0, (size_t)NN * 4, stream);
    k_count<<<eblk, b256, 0, stream>>>(dst, cnt);
    k_scan1<<<SNBLK, b256, 0, stream>>>(cnt, rowptr, blksum);
    k_scan2<<<1, b128, 0, stream>>>(blksum);
    k_scan3<<<nblk, b256, 0, stream>>>(blksum, cnt, rowptr, cursor, invdeg);
    k_fill<<<eblk, b256, 0, stream>>>(src, dst, cursor, colsrc);

    // ---- front ----
    k_n2vp_t<<<NT, b256, 0, stream>>>(n2v, n2v_w, n2v_b, n2vp);
    k_front_t<<<NT, b256, 0, stream>>>(x, n2vp, ip_w, ip_b, gate_w, gate_b, S2);

    // ---- SAGE 0: S2 -> S1 ----
    k_gather_mean<<<2048, b256, 0, stream>>>(rowptr, colsrc, invdeg, S2, agg);
    k_sage_t<<<NT, b256, 0, stream>>>(agg, S2, s0_wl, s0_bl, s0_wr, S1);

    // ---- SAGE 1: S1 -> S2 ----
    k_gather_mean<<<2048, b256, 0, stream>>>(rowptr, colsrc, invdeg, S1, agg);
    k_sage_t<<<NT, b256, 0, stream>>>(agg, S1, s1_wl, s1_bl, s1_wr, S2);

    // ---- GAT: S2 -> S1 ----
    k_gatxh_t<<<NT, b256, 0, stream>>>(S2, gat_w, att_s, att_d, xh, a_s, a_d);
    k_gat_fused<<<2048, b256, 0, stream>>>(rowptr, colsrc, a_s, a_d, xh, gat_b, S1);

    // ---- final SAGE: S1 -> out ----
    k_pfin<<<2048, b256, 0, stream>>>(S1, f_wl, P);
    k_final_fused<<<2048, b256, 0, stream>>>(rowptr, colsrc, invdeg, P, S1, f_bl, f_wr, out);
}